// Round 2
// baseline (181.614 us; speedup 1.0000x reference)
//
#include <hip/hip_runtime.h>
#include <math.h>

// ---------------------------------------------------------------------------
// TwoDimEquivalent: B=8192 independent nonlinear scans of length T=2048.
// Key ideas:
//  * gauss_int depends only on s = delta^2  ->  1-D lerp table in LDS
//    (table = exact 64-pt Gauss-Legendre sum, nodes solved on device).
//  * dynamics contract ~0.93/step  ->  split T into 16 chunks of 128 steps,
//    each chunk re-warmed from zero state 128 steps early (init error ~1e-4).
//  * u reads / z writes staged through LDS tiles for coalescing (row strides
//    2048/2049 floats are hostile to direct per-thread access).
// R1 bug: grid expression evaluated to 256, not 512 -> chunks 8..15 missing.
// ---------------------------------------------------------------------------

#define Bsz   8192
#define Tlen  2048
#define TP1   2049
#define NQ    64
#define NTAB  8192
#define INV_H 128.0f              // NTAB / S_MAX, S_MAX = 64 (delta up to 8)
#define CHUNKS 16
#define CLEN  128                 // Tlen / CHUNKS
#define WARM  128                 // warmup steps per chunk
#define BLOCK 256
#define TSTEP 8
#define SIM_GRID 512              // (Bsz/BLOCK row-blocks = 32) * CHUNKS = 512

#define WS_TAB 128                // table offset (floats) inside d_ws

// --------------------------- setup: build LUT ------------------------------
__global__ __launch_bounds__(256) void setup_kernel(float* __restrict__ ws,
                                                    float* __restrict__ out) {
    __shared__ float  fx[NQ], fw[NQ];
    __shared__ double inv[NQ + 1];
    const int tid = threadIdx.x;
    if (tid <= NQ) inv[tid] = (tid == 0) ? 0.0 : 1.0 / (double)tid;
    __syncthreads();
    if (tid < NQ) {
        // Newton on P_64 (gauleg); guess good to ~3e-4, 6 iters -> ~1e-15
        double z = cos(3.14159265358979323846 * (tid + 0.75) / (NQ + 0.5));
        double p1 = 1.0, p2 = 0.0;
        for (int it = 0; it < 6; ++it) {
            p1 = 1.0; p2 = 0.0;
            for (int j = 1; j <= NQ; ++j) {
                double p3 = p2; p2 = p1;
                p1 = ((2.0 * j - 1.0) * z * p2 - (j - 1.0) * p3) * inv[j];
            }
            double pp = NQ * (z * p1 - p2) / (z * z - 1.0);
            z -= p1 / pp;
        }
        p1 = 1.0; p2 = 0.0;
        for (int j = 1; j <= NQ; ++j) {
            double p3 = p2; p2 = p1;
            p1 = ((2.0 * j - 1.0) * z * p2 - (j - 1.0) * p3) * inv[j];
        }
        double pp = NQ * (z * p1 - p2) / (z * z - 1.0);
        double w  = 2.0 / ((1.0 - z * z) * pp * pp);
        double xs = z * 5.0;                       // node scaled to [-5,5]
        fx[tid] = (float)xs;                       // f32 cast, like reference
        fw[tid] = (float)(w * 5.0 * exp(-0.5 * xs * xs) * 0.3989422804014327);
    }
    __syncthreads();
    // table entry e: s = e/128, g = sum_q w_q * (1 - tanh(sqrt(s)*x_q)^2)
    const int e = blockIdx.x * BLOCK + tid;        // grid is 32x256 = 8192
    const float d = sqrtf((float)e * (1.0f / INV_H));
    float acc = 0.0f;
    #pragma unroll 8
    for (int q = 0; q < NQ; ++q) {
        float t = tanhf(d * fx[q]);
        acc = fmaf(fw[q], 1.0f - t * t, acc);
    }
    ws[WS_TAB + e] = acc;
    out[(size_t)e * TP1] = 0.0f;                   // z_hist[:,0] = 0
}

// ------------------------------ main scan ----------------------------------
__device__ __forceinline__ float step_one(float uu, float& k1, float& k2,
                                          float& v, const float* s_tab) {
    float s   = fmaf(k1, k1, fmaf(k2, k2, uu * uu));      // delta^2
    float idx = fminf(s * INV_H, (float)(NTAB - 2));
    int   i0  = (int)idx;
    float f   = idx - (float)i0;
    float g0  = s_tab[i0];
    float g1  = s_tab[i0 + 1];
    float g   = fmaf(f, g1 - g0, g0);                     // gauss_int
    float gv  = g * v;
    float nk1 = fmaf(k1, fmaf(0.2f, g, 0.8f), 0.10f * gv);
    float nk2 = fmaf(k2, fmaf(0.1f, g, 0.8f), 0.38f * gv);
    v  = fmaf(0.2f, uu - v, v);
    k1 = nk1; k2 = nk2;
    return fmaf(2.8f, nk1, -2.2f * nk2);
}

__global__ __launch_bounds__(BLOCK, 2) void sim_kernel(const float* __restrict__ u,
                                                       const float* __restrict__ ws,
                                                       float* __restrict__ out) {
    __shared__ float  s_tab[NTAB];                 // 32 KB
    __shared__ float2 s_u2[4][BLOCK];              // 8 KB, [t-pair][row]
    __shared__ float2 s_z2[4][BLOCK + 8];          // 8.25 KB (pad kills flush conflicts)
    const int tid = threadIdx.x;

    {   // table -> LDS, coalesced float4
        const float4* src = (const float4*)(ws + WS_TAB);
        float4* dst = (float4*)s_tab;
        #pragma unroll
        for (int k = 0; k < NTAB / 4 / BLOCK; ++k)
            dst[tid + k * BLOCK] = src[tid + k * BLOCK];
    }

    const int c    = blockIdx.x >> 5;              // chunk id (16)
    const int bb   = blockIdx.x & 31;              // row-block id (32)
    const int rowb = bb * BLOCK;
    const int t_out   = c * CLEN;                  // first owned step
    const int t_end   = t_out + CLEN;
    const int t_begin = (c == 0) ? 0 : (t_out - WARM);

    float k1 = 0.f, k2 = 0.f, v = 0.f, zp = 0.f;   // zp: z of previous step
    const int r1 = tid >> 1;
    const int h4 = (tid & 1) * 4;
    const int ph = (tid & 1) * 2;
    const float* zs = (const float*)s_z2;          // dword view, row stride 528

    for (int tb = t_begin; tb < t_end; tb += TSTEP) {
        __syncthreads();                           // tiles free for reuse
        // stage u[rowb..rowb+255][tb..tb+8): two coalesced float4 per thread
        const float* up = u + (size_t)(rowb + r1) * Tlen + tb + h4;
        float4 Ua = *(const float4*)up;
        float4 Ub = *(const float4*)(up + 128 * Tlen);
        s_u2[ph    ][r1      ] = make_float2(Ua.x, Ua.y);
        s_u2[ph + 1][r1      ] = make_float2(Ua.z, Ua.w);
        s_u2[ph    ][r1 + 128] = make_float2(Ub.x, Ub.y);
        s_u2[ph + 1][r1 + 128] = make_float2(Ub.z, Ub.w);
        __syncthreads();
        const bool outg = (tb >= t_out);           // uniform per block
        #pragma unroll
        for (int p = 0; p < 4; ++p) {
            float2 uu = s_u2[p][tid];
            float za = step_one(uu.x, k1, k2, v, s_tab);
            float zb = step_one(uu.y, k1, k2, v, s_tab);
            // tile covers OUTPUT cols [tb, tb+8); col t+1 <- z of step t,
            // so slot 2p gets previous z, slot 2p+1 gets za; zb carries over.
            if (outg) s_z2[p][tid] = make_float2(zp, za);
            zp = zb;
        }
        if (outg) {
            __syncthreads();                       // z tile complete
            const int r0   = tid >> 3;
            const int sf   = tid & 7;
            const int lofs = (sf >> 1) * 2 * (BLOCK + 8) + (sf & 1);
            if (tb == t_out) {                     // first group: col tb not ours
                if (sf != 0) {
                    #pragma unroll
                    for (int q = 0; q < 8; ++q) {
                        int r = r0 + 32 * q;
                        out[(size_t)(rowb + r) * TP1 + tb + sf] = zs[lofs + 2 * r];
                    }
                }
            } else {                               // full 8-col flush, 32B rows
                #pragma unroll
                for (int q = 0; q < 8; ++q) {
                    int r = r0 + 32 * q;
                    out[(size_t)(rowb + r) * TP1 + tb + sf] = zs[lofs + 2 * r];
                }
            }
        }
    }
    // last produced z (col t_end) never went through a tile
    out[(size_t)(rowb + tid) * TP1 + t_end] = zp;
}

// ------------------------------ launcher -----------------------------------
extern "C" void kernel_launch(void* const* d_in, const int* in_sizes, int n_in,
                              void* d_out, int out_size, void* d_ws, size_t ws_size,
                              hipStream_t stream) {
    const float* u = (const float*)d_in[0];
    float* out = (float*)d_out;
    float* ws  = (float*)d_ws;                     // needs ~33 KB
    setup_kernel<<<32, BLOCK, 0, stream>>>(ws, out);
    sim_kernel<<<SIM_GRID, BLOCK, 0, stream>>>(u, ws, out);
}